// Round 18
// baseline (58.599 us; speedup 1.0000x reference)
//
#include <hip/hip_runtime.h>

#define NB   8192
#define NA   32
#define DIN  8
#define HID  64
#define DOUT 8

typedef float     v4f __attribute__((ext_vector_type(4)));
typedef __fp16    v2fp __attribute__((ext_vector_type(2)));
typedef _Float16  v2h __attribute__((ext_vector_type(2)));
typedef _Float16  v4h __attribute__((ext_vector_type(4)));
typedef _Float16  v8h __attribute__((ext_vector_type(8)));

__device__ __forceinline__ float silu_f(float x) {
    return __fdividef(x, 1.0f + __expf(-x));
}

__device__ __forceinline__ v2h pkrtz(float a, float b) {
    v2fp r = __builtin_amdgcn_cvt_pkrtz(a, b);
    return __builtin_bit_cast(v2h, r);
}

__device__ __forceinline__ v4h cvt4(v4f a) {
    v2h lo = pkrtz(a[0], a[1]);
    v2h hi = pkrtz(a[2], a[3]);
    return __builtin_shufflevector(lo, hi, 0, 1, 2, 3);
}

__device__ __forceinline__ v8h cvt8(v4f a, v4f b) {
    v4h x = cvt4(a);
    v4h y = cvt4(b);
    return __builtin_shufflevector(x, y, 0, 1, 2, 3, 4, 5, 6, 7);
}

__device__ __forceinline__ v4h silu_cvt4(v4f a) {
    v4f s;
    s[0] = silu_f(a[0]); s[1] = silu_f(a[1]);
    s[2] = silu_f(a[2]); s[3] = silu_f(a[3]);
    return cvt4(s);
}

__device__ __forceinline__ v8h cat(v4h a, v4h b) {
    return __builtin_shufflevector(a, b, 0, 1, 2, 3, 4, 5, 6, 7);
}

// Known-good reductions (r16): shfl butterfly. permlane*_swap is BANNED here:
// both the raw asm (r15) and the builtin (r17) NaN'd -- same-source operands
// get register-coalesced and the swap semantics collapse.
__device__ __forceinline__ float redmax64(float x) {
    x = fmaxf(x, __shfl_xor(x, 16, 64));
    return fmaxf(x, __shfl_xor(x, 32, 64));
}
__device__ __forceinline__ float redsum64(float x) {
    x += __shfl_xor(x, 16, 64);
    return x + __shfl_xor(x, 32, 64);
}

#define MFMA16(A, B, C) __builtin_amdgcn_mfma_f32_16x16x16f16((A), (B), (C), 0, 0, 0)
#define MFMA32(A, B, C) __builtin_amdgcn_mfma_f32_16x16x32_f16((A), (B), (C), 0, 0, 0)

// TWO items per wave (ILP), zero per-item LDS, swapped h-gemm, K=32 MFMAs.
// This round: softmax denominator via MFMA rowsum (E @ ones) on the idle
// matrix pipe; normalization deferred past PV (pv * rcp(sum) per-reg).
// Removes the serial 16-add + 2-shfl sum chain from the S->PV critical path.
__global__ __launch_bounds__(256, 2) void attn_mfma_kernel(
    const float* __restrict__ x,      // (NB, NA, DIN)
    const float* __restrict__ lap,    // (NB, NA)
    const float* __restrict__ W_in,   // (HID, DIN)
    const float* __restrict__ b_in,   // (HID)
    const float* __restrict__ Aq,     // (HID, HID)
    const float* __restrict__ Ak,     // (HID, HID)
    const float* __restrict__ Av,     // (HID, HID)
    const float* __restrict__ W_out,  // (DOUT, HID)
    const float* __restrict__ b_out,  // (DOUT)
    float* __restrict__ out)          // (NB, DOUT)
{
    // Paired frag-ordered f16 weights: [mat][it*2+c][lane][8]   (24 KB)
    __shared__ _Float16 wlds[3][8][64][8];

    const int t  = threadIdx.x;
    const int l  = t & 63;
    const int w  = t >> 6;          // 0..3
    const int lm = l & 15;
    const int lg = l >> 4;

    // ---- stage Aq/Ak/Av into LDS as paired f16 frags (2 fids per wave) ----
    {
        const float* mats[3] = {Aq, Ak, Av};
        #pragma unroll
        for (int m = 0; m < 3; ++m)
            #pragma unroll
            for (int f = 0; f < 2; ++f) {
                const int fid = w * 2 + f;          // it = w, c = f
                const float* base = mats[m] + (lm + 16 * w) * 64 + 32 * f + 4 * lg;
                *(v8h*)&wlds[m][fid][l][0] =
                    cvt8(*(const v4f*)base, *(const v4f*)(base + 16));
            }
    }

    // ---- persistent register frags (shared across both items) ----
    v4h zh = {};
    v4f zf = {};
    v4h winf[4];
    #pragma unroll
    for (int jt = 0; jt < 4; ++jt) {
        v4h wf = zh;
        if (lg < 2)       wf = cvt4(*(const v4f*)(W_in + (lm + 16 * jt) * 8 + 4 * lg));
        else if (lg == 2) wf[0] = (_Float16)b_in[lm + 16 * jt];
        winf[jt] = wf;
    }
    v4h woutf[4];
    #pragma unroll
    for (int ks = 0; ks < 4; ++ks)
        woutf[ks] = (lm < 8) ? cvt4(*(const v4f*)(W_out + lm * 64 + 16 * ks + 4 * lg)) : zh;
    const float boutf = (lm < 8) ? b_out[lm] : 0.0f;
    v4h onef = zh;
    if (lg == 2) onef[0] = (_Float16)1.0f;   // the k=8 "bias column" of x
    v8h ones8;
    #pragma unroll
    for (int i = 0; i < 8; ++i) ones8[i] = (_Float16)1.0f;

    __syncthreads();   // the only block barrier

    const int b0 = blockIdx.x * 8 + w * 2;   // items b0, b0+1 (1024*4*2 == NB)

    v4f  lapv[2][2];
    float lap_n[2][2];
    v4h  xf_[2][2];
    #pragma unroll
    for (int u = 0; u < 2; ++u) {
        const int b = b0 + u;
        lapv[u][0] = *(const v4f*)(lap + b * 32 + 4 * lg);
        lapv[u][1] = *(const v4f*)(lap + b * 32 + 16 + 4 * lg);
        lap_n[u][0] = lap[b * 32 + lm];
        lap_n[u][1] = lap[b * 32 + 16 + lm];
        #pragma unroll
        for (int nt = 0; nt < 2; ++nt)
            xf_[u][nt] = (lg < 2)
                ? cvt4(*(const v4f*)(x + b * 256 + (lm + 16 * nt) * 8 + 4 * lg))
                : onef;
    }

    // ---- h^T: C[jt][nt] reg r = h[n=lm+16nt][j=4lg+r+16jt], both items ----
    v8h hf8[2][2][2];   // [u][nt][c]
    #pragma unroll
    for (int u = 0; u < 2; ++u)
        #pragma unroll
        for (int nt = 0; nt < 2; ++nt)
            #pragma unroll
            for (int c = 0; c < 2; ++c) {
                v4f h0 = MFMA16(winf[2 * c],     xf_[u][nt], zf);
                v4f h1 = MFMA16(winf[2 * c + 1], xf_[u][nt], zf);
                v4f s0, s1;
                #pragma unroll
                for (int r = 0; r < 4; ++r) {
                    s0[r] = silu_f(h0[r]) * lap_n[u][nt];
                    s1[r] = silu_f(h1[r]) * lap_n[u][nt];
                }
                hf8[u][nt][c] = cat(cvt4(s0), cvt4(s1));
            }

    // ---- QT[n][i] = silu(h @ Aq^T), per-it accs, weights read once ----
    v8h qf8[2][4];
    #pragma unroll
    for (int it = 0; it < 4; ++it) {
        v4f a_[2][2] = {};   // [u][nt]
        #pragma unroll
        for (int c = 0; c < 2; ++c) {
            v8h bw = *(v8h*)&wlds[0][it * 2 + c][l][0];
            #pragma unroll
            for (int u = 0; u < 2; ++u)
                #pragma unroll
                for (int nt = 0; nt < 2; ++nt)
                    a_[u][nt] = MFMA32(hf8[u][nt][c], bw, a_[u][nt]);
        }
        #pragma unroll
        for (int u = 0; u < 2; ++u)
            qf8[u][it] = cat(silu_cvt4(a_[u][0]), silu_cvt4(a_[u][1]));
    }
    // ---- KT[n][i] = silu(h @ Ak^T) ----
    v8h kf8[2][4];
    #pragma unroll
    for (int it = 0; it < 4; ++it) {
        v4f a_[2][2] = {};
        #pragma unroll
        for (int c = 0; c < 2; ++c) {
            v8h bw = *(v8h*)&wlds[1][it * 2 + c][l][0];
            #pragma unroll
            for (int u = 0; u < 2; ++u)
                #pragma unroll
                for (int nt = 0; nt < 2; ++nt)
                    a_[u][nt] = MFMA32(hf8[u][nt][c], bw, a_[u][nt]);
        }
        #pragma unroll
        for (int u = 0; u < 2; ++u)
            kf8[u][it] = cat(silu_cvt4(a_[u][0]), silu_cvt4(a_[u][1]));
    }
    // ---- V[i][n] = silu(Av @ h^T), paired over it into j-chunks ----
    v8h vf8[2][2][2];   // [u][cp][nt]
    #pragma unroll
    for (int cp = 0; cp < 2; ++cp) {
        v4f a_[2][2][2] = {};   // [its][u][nt]
        #pragma unroll
        for (int its = 0; its < 2; ++its) {
            const int it = cp * 2 + its;
            #pragma unroll
            for (int c = 0; c < 2; ++c) {
                v8h aw = *(v8h*)&wlds[2][it * 2 + c][l][0];
                #pragma unroll
                for (int u = 0; u < 2; ++u)
                    #pragma unroll
                    for (int nt = 0; nt < 2; ++nt)
                        a_[its][u][nt] = MFMA32(aw, hf8[u][nt][c], a_[its][u][nt]);
            }
        }
        #pragma unroll
        for (int u = 0; u < 2; ++u)
            #pragma unroll
            for (int nt = 0; nt < 2; ++nt)
                vf8[u][cp][nt] = cat(silu_cvt4(a_[0][u][nt]), silu_cvt4(a_[1][u][nt]));
    }

    // ---- streamed tail: per i-tile x item ----
    // S -> max -> E=exp(S-mx) -> f16 (unnormalized, <=1) -> PV and
    // rowsum = E @ ones on the MFMA pipe -> normalize pv by rcp(sum) per reg.
    v4f ya[2][2] = {};   // [u][nt]
    #pragma unroll
    for (int it = 0; it < 4; ++it)
        #pragma unroll
        for (int u = 0; u < 2; ++u) {
            v4f s[4];
            #pragma unroll
            for (int jt = 0; jt < 4; ++jt)
                s[jt] = MFMA32(kf8[u][jt], qf8[u][it], zf);

            float mx = fmaxf(fmaxf(fmaxf(s[0][0], s[0][1]), fmaxf(s[0][2], s[0][3])),
                             fmaxf(fmaxf(s[1][0], s[1][1]), fmaxf(s[1][2], s[1][3])));
            float mx2 = fmaxf(fmaxf(fmaxf(s[2][0], s[2][1]), fmaxf(s[2][2], s[2][3])),
                              fmaxf(fmaxf(s[3][0], s[3][1]), fmaxf(s[3][2], s[3][3])));
            mx = redmax64(fmaxf(mx, mx2));

            v4h pf[4];   // E in f16, unnormalized (values in (0,1])
            #pragma unroll
            for (int jt = 0; jt < 4; ++jt) {
                v4f e;
                #pragma unroll
                for (int r = 0; r < 4; ++r) e[r] = __expf(s[jt][r] - mx);
                pf[jt] = cvt4(e);
            }

            v4f pv[2] = {};
            v4f sums = zf;
            #pragma unroll
            for (int c = 0; c < 2; ++c) {
                v8h pf8 = cat(pf[2 * c], pf[2 * c + 1]);
                #pragma unroll
                for (int nt = 0; nt < 2; ++nt)
                    pv[nt] = MFMA32(pf8, vf8[u][c][nt], pv[nt]);
                sums = MFMA32(pf8, ones8, sums);   // C[i][*]: reg r -> i=4lg+r
            }

            v4f inv;
            #pragma unroll
            for (int r = 0; r < 4; ++r) inv[r] = __fdividef(1.0f, sums[r]);
            #pragma unroll
            for (int nt = 0; nt < 2; ++nt) {
                v4f a;
                #pragma unroll
                for (int r = 0; r < 4; ++r) a[r] = silu_f(pv[nt][r] * inv[r]);
                ya[u][nt] = MFMA16(cvt4(a), woutf[it], ya[u][nt]);
            }
        }

    // ---- y = silu(ya + b_out) * lap ; mean over n ; store per item ----
    #pragma unroll
    for (int u = 0; u < 2; ++u) {
        float acc = 0.0f;
        #pragma unroll
        for (int nt = 0; nt < 2; ++nt)
            #pragma unroll
            for (int r = 0; r < 4; ++r)
                acc += silu_f(ya[u][nt][r] + boutf) * lapv[u][nt][r];
        acc = redsum64(acc);
        if (l < 8) out[(b0 + u) * DOUT + l] = acc * (1.0f / NA);
    }
}

extern "C" void kernel_launch(void* const* d_in, const int* in_sizes, int n_in,
                              void* d_out, int out_size, void* d_ws, size_t ws_size,
                              hipStream_t stream) {
    const float* x     = (const float*)d_in[0];
    const float* lap   = (const float*)d_in[1];
    const float* W_in  = (const float*)d_in[2];
    const float* b_in  = (const float*)d_in[3];
    const float* Aq    = (const float*)d_in[4];
    const float* Ak    = (const float*)d_in[5];
    const float* Av    = (const float*)d_in[6];
    const float* W_out = (const float*)d_in[7];
    const float* b_out = (const float*)d_in[8];
    attn_mfma_kernel<<<1024, 256, 0, stream>>>(x, lap, W_in, b_in, Aq, Ak, Av,
                                               W_out, b_out, (float*)d_out);
}

// Round 19
// 56.548 us; speedup vs baseline: 1.0363x; 1.0363x over previous
//
#include <hip/hip_runtime.h>

#define NB   8192
#define NA   32
#define DIN  8
#define HID  64
#define DOUT 8

typedef float     v4f __attribute__((ext_vector_type(4)));
typedef __fp16    v2fp __attribute__((ext_vector_type(2)));
typedef _Float16  v2h __attribute__((ext_vector_type(2)));
typedef _Float16  v4h __attribute__((ext_vector_type(4)));
typedef _Float16  v8h __attribute__((ext_vector_type(8)));

__device__ __forceinline__ float silu_f(float x) {
    return __fdividef(x, 1.0f + __expf(-x));
}

__device__ __forceinline__ v2h pkrtz(float a, float b) {
    v2fp r = __builtin_amdgcn_cvt_pkrtz(a, b);
    return __builtin_bit_cast(v2h, r);
}

__device__ __forceinline__ v4h cvt4(v4f a) {
    v2h lo = pkrtz(a[0], a[1]);
    v2h hi = pkrtz(a[2], a[3]);
    return __builtin_shufflevector(lo, hi, 0, 1, 2, 3);
}

__device__ __forceinline__ v8h cvt8(v4f a, v4f b) {
    v4h x = cvt4(a);
    v4h y = cvt4(b);
    return __builtin_shufflevector(x, y, 0, 1, 2, 3, 4, 5, 6, 7);
}

__device__ __forceinline__ v4h silu_cvt4(v4f a) {
    v4f s;
    s[0] = silu_f(a[0]); s[1] = silu_f(a[1]);
    s[2] = silu_f(a[2]); s[3] = silu_f(a[3]);
    return cvt4(s);
}

__device__ __forceinline__ v8h cat(v4h a, v4h b) {
    return __builtin_shufflevector(a, b, 0, 1, 2, 3, 4, 5, 6, 7);
}

// Known-good reductions (r16). permlane*_swap BANNED (r15/r17 NaN).
__device__ __forceinline__ float redmax64(float x) {
    x = fmaxf(x, __shfl_xor(x, 16, 64));
    return fmaxf(x, __shfl_xor(x, 32, 64));
}
__device__ __forceinline__ float redsum64(float x) {
    x += __shfl_xor(x, 16, 64);
    return x + __shfl_xor(x, 32, 64);
}

#define MFMA16(A, B, C) __builtin_amdgcn_mfma_f32_16x16x16f16((A), (B), (C), 0, 0, 0)
#define MFMA32(A, B, C) __builtin_amdgcn_mfma_f32_16x16x32_f16((A), (B), (C), 0, 0, 0)

// ONE item per wave; register diet to cross the 128-reg occupancy cliff
// (waves/SIMD halve at total VGPR+AGPR {64,128,256}; r10-r18 sat in
// (128,256] -> 2 waves/SIMD, latency-bound). Tail-only values (woutf,
// lapv, boutf) are loaded AFTER Q/K/V so their liveness doesn't span
// the gemm phase. Target total <=128 -> 4 waves/SIMD.
__global__ __launch_bounds__(256, 4) void attn_mfma_kernel(
    const float* __restrict__ x,      // (NB, NA, DIN)
    const float* __restrict__ lap,    // (NB, NA)
    const float* __restrict__ W_in,   // (HID, DIN)
    const float* __restrict__ b_in,   // (HID)
    const float* __restrict__ Aq,     // (HID, HID)
    const float* __restrict__ Ak,     // (HID, HID)
    const float* __restrict__ Av,     // (HID, HID)
    const float* __restrict__ W_out,  // (DOUT, HID)
    const float* __restrict__ b_out,  // (DOUT)
    float* __restrict__ out)          // (NB, DOUT)
{
    // Paired frag-ordered f16 weights: [mat][it*2+c][lane][8]   (24 KB)
    __shared__ _Float16 wlds[3][8][64][8];

    const int t  = threadIdx.x;
    const int l  = t & 63;
    const int w  = t >> 6;          // 0..3
    const int lm = l & 15;
    const int lg = l >> 4;

    // ---- stage Aq/Ak/Av into LDS as paired f16 frags (2 fids per wave) ----
    {
        const float* mats[3] = {Aq, Ak, Av};
        #pragma unroll
        for (int m = 0; m < 3; ++m)
            #pragma unroll
            for (int f = 0; f < 2; ++f) {
                const int fid = w * 2 + f;          // it = w, c = f
                const float* base = mats[m] + (lm + 16 * w) * 64 + 32 * f + 4 * lg;
                *(v8h*)&wlds[m][fid][l][0] =
                    cvt8(*(const v4f*)base, *(const v4f*)(base + 16));
            }
    }

    // ---- h-stage register frags only (tail values loaded later) ----
    v4h zh = {};
    v4f zf = {};
    v4h winf[4];
    #pragma unroll
    for (int jt = 0; jt < 4; ++jt) {
        v4h wf = zh;
        if (lg < 2)       wf = cvt4(*(const v4f*)(W_in + (lm + 16 * jt) * 8 + 4 * lg));
        else if (lg == 2) wf[0] = (_Float16)b_in[lm + 16 * jt];
        winf[jt] = wf;
    }
    v4h onef = zh;
    if (lg == 2) onef[0] = (_Float16)1.0f;   // the k=8 "bias column" of x

    __syncthreads();   // the only block barrier

    const int b = blockIdx.x * 4 + w;   // one item per wave, 2048*4 == NB

    float lap_n[2];                      // lap by lane n=lm+16nt (h stage)
    lap_n[0] = lap[b * 32 + lm];
    lap_n[1] = lap[b * 32 + 16 + lm];

    // xf[nt]: B-frag x^T[k=d][n=lm+16nt]; k=8 slot = 1.0 (bias column)
    v4h xf[2];
    #pragma unroll
    for (int nt = 0; nt < 2; ++nt)
        xf[nt] = (lg < 2) ? cvt4(*(const v4f*)(x + b * 256 + (lm + 16 * nt) * 8 + 4 * lg))
                          : onef;

    // ---- h^T: C[jt][nt] reg r = h[n=lm+16nt][j=4lg+r+16jt] ----
    v8h hf8[2][2];
    #pragma unroll
    for (int nt = 0; nt < 2; ++nt)
        #pragma unroll
        for (int c = 0; c < 2; ++c) {
            v4f h0 = MFMA16(winf[2 * c],     xf[nt], zf);
            v4f h1 = MFMA16(winf[2 * c + 1], xf[nt], zf);
            v4f s0, s1;
            #pragma unroll
            for (int r = 0; r < 4; ++r) {
                s0[r] = silu_f(h0[r]) * lap_n[nt];
                s1[r] = silu_f(h1[r]) * lap_n[nt];
            }
            hf8[nt][c] = cat(cvt4(s0), cvt4(s1));
        }

    // ---- QT[n][i] = silu(h @ Aq^T)  (K=32) ----
    v8h qf8[4];
    {
        v4f acc[2][4] = {};
        #pragma unroll
        for (int it = 0; it < 4; ++it)
            #pragma unroll
            for (int c = 0; c < 2; ++c) {
                v8h bw = *(v8h*)&wlds[0][it * 2 + c][l][0];
                #pragma unroll
                for (int nt = 0; nt < 2; ++nt)
                    acc[nt][it] = MFMA32(hf8[nt][c], bw, acc[nt][it]);
            }
        #pragma unroll
        for (int it = 0; it < 4; ++it)
            qf8[it] = cat(silu_cvt4(acc[0][it]), silu_cvt4(acc[1][it]));
    }
    // ---- KT[n][i] = silu(h @ Ak^T) ----
    v8h kf8[4];
    {
        v4f acc[2][4] = {};
        #pragma unroll
        for (int it = 0; it < 4; ++it)
            #pragma unroll
            for (int c = 0; c < 2; ++c) {
                v8h bw = *(v8h*)&wlds[1][it * 2 + c][l][0];
                #pragma unroll
                for (int nt = 0; nt < 2; ++nt)
                    acc[nt][it] = MFMA32(hf8[nt][c], bw, acc[nt][it]);
            }
        #pragma unroll
        for (int it = 0; it < 4; ++it)
            kf8[it] = cat(silu_cvt4(acc[0][it]), silu_cvt4(acc[1][it]));
    }
    // ---- V[i][n] = silu(Av @ h^T) ----  (h dies here)
    v8h vf8[2][2];
    {
        v4f acc[4][2] = {};
        #pragma unroll
        for (int it = 0; it < 4; ++it)
            #pragma unroll
            for (int c = 0; c < 2; ++c) {
                v8h aw = *(v8h*)&wlds[2][it * 2 + c][l][0];
                #pragma unroll
                for (int nt = 0; nt < 2; ++nt)
                    acc[it][nt] = MFMA32(aw, hf8[nt][c], acc[it][nt]);
            }
        #pragma unroll
        for (int c = 0; c < 2; ++c)
            #pragma unroll
            for (int nt = 0; nt < 2; ++nt)
                vf8[c][nt] = cat(silu_cvt4(acc[2 * c][nt]), silu_cvt4(acc[2 * c + 1][nt]));
    }

    // ---- tail-only loads (liveness starts here, not at kernel entry) ----
    v4h woutf[4];
    #pragma unroll
    for (int ks = 0; ks < 4; ++ks)
        woutf[ks] = (lm < 8) ? cvt4(*(const v4f*)(W_out + lm * 64 + 16 * ks + 4 * lg)) : zh;
    const float boutf = (lm < 8) ? b_out[lm] : 0.0f;
    v4f lapv[2];
    lapv[0] = *(const v4f*)(lap + b * 32 + 4 * lg);
    lapv[1] = *(const v4f*)(lap + b * 32 + 16 + 4 * lg);

    // ---- streamed tail: per i-tile, S-col -> softmax -> PV -> Wout-acc ----
    v4f ya[2] = {};
    #pragma unroll
    for (int it = 0; it < 4; ++it) {
        v4f s[4];
        #pragma unroll
        for (int jt = 0; jt < 4; ++jt)
            s[jt] = MFMA32(kf8[jt], qf8[it], zf);

        float mx = fmaxf(fmaxf(fmaxf(s[0][0], s[0][1]), fmaxf(s[0][2], s[0][3])),
                         fmaxf(fmaxf(s[1][0], s[1][1]), fmaxf(s[1][2], s[1][3])));
        float mx2 = fmaxf(fmaxf(fmaxf(s[2][0], s[2][1]), fmaxf(s[2][2], s[2][3])),
                          fmaxf(fmaxf(s[3][0], s[3][1]), fmaxf(s[3][2], s[3][3])));
        mx = redmax64(fmaxf(mx, mx2));
        float sum = 0.0f;
        #pragma unroll
        for (int jt = 0; jt < 4; ++jt)
            #pragma unroll
            for (int r = 0; r < 4; ++r) {
                float e = __expf(s[jt][r] - mx);
                s[jt][r] = e;
                sum += e;
            }
        sum = redsum64(sum);
        const float inv = __fdividef(1.0f, sum);
        v4h pf[4];
        #pragma unroll
        for (int jt = 0; jt < 4; ++jt) pf[jt] = cvt4(s[jt] * inv);

        v4f pv[2] = {};
        #pragma unroll
        for (int c = 0; c < 2; ++c) {
            v8h pf8 = cat(pf[2 * c], pf[2 * c + 1]);
            #pragma unroll
            for (int nt = 0; nt < 2; ++nt)
                pv[nt] = MFMA32(pf8, vf8[c][nt], pv[nt]);
        }
        #pragma unroll
        for (int nt = 0; nt < 2; ++nt)
            ya[nt] = MFMA16(silu_cvt4(pv[nt]), woutf[it], ya[nt]);
    }

    // ---- y = silu(ya + b_out) * lap ; mean over n ----
    float acc = 0.0f;
    #pragma unroll
    for (int nt = 0; nt < 2; ++nt)
        #pragma unroll
        for (int r = 0; r < 4; ++r)
            acc += silu_f(ya[nt][r] + boutf) * lapv[nt][r];
    acc = redsum64(acc);
    if (l < 8) out[b * DOUT + l] = acc * (1.0f / NA);
}

extern "C" void kernel_launch(void* const* d_in, const int* in_sizes, int n_in,
                              void* d_out, int out_size, void* d_ws, size_t ws_size,
                              hipStream_t stream) {
    const float* x     = (const float*)d_in[0];
    const float* lap   = (const float*)d_in[1];
    const float* W_in  = (const float*)d_in[2];
    const float* b_in  = (const float*)d_in[3];
    const float* Aq    = (const float*)d_in[4];
    const float* Ak    = (const float*)d_in[5];
    const float* Av    = (const float*)d_in[6];
    const float* W_out = (const float*)d_in[7];
    const float* b_out = (const float*)d_in[8];
    attn_mfma_kernel<<<2048, 256, 0, stream>>>(x, lap, W_in, b_in, Aq, Ak, Av,
                                               W_out, b_out, (float*)d_out);
}